// Round 2
// baseline (141.096 us; speedup 1.0000x reference)
//
#include <hip/hip_runtime.h>
#include <hip/hip_fp16.h>

// Problem constants
#define OOv   200
#define KKv   1600
#define OPAD  208             // 13 col-tiles of 16
#define NCHUNK 50             // K=32 chunks
#define CHUNK_BYTES 13312     // one K=32 chunk of W-fp16 (208*4 slots * 16B)
#define XSTR 40               // halfs per x row (80 B, mult of 16)
#define YSTR 56               // halfs per y row (112 B; 28-dw stride = 2-way banks, free)

typedef _Float16 half8  __attribute__((ext_vector_type(8)));
typedef _Float16 half2v __attribute__((ext_vector_type(2)));
typedef __attribute__((ext_vector_type(4))) float floatx4;

// ---------------------------------------------------------------------------
// Pre-kernel: W [200][1600] fp32 -> Wh fp16, K-chunk-major, 16B-slot swizzled.
// idx = c*6656 + slot*8 + j ; slot = o*4 + (kg ^ ((o>>1)&3)) ; k = c*32+kg*8+j
// ---------------------------------------------------------------------------
__global__ void wb_convert_kernel(const float* __restrict__ W,
                                  unsigned short* __restrict__ Wh) {
    int idx = blockIdx.x * 256 + threadIdx.x;
    if (idx >= NCHUNK * OPAD * 32) return;     // 332800
    int j    = idx & 7;
    int slot = (idx >> 3) % (OPAD * 4);
    int c    = (idx >> 3) / (OPAD * 4);
    int o    = slot >> 2;
    int kgs  = slot & 3;
    int kg   = kgs ^ ((o >> 1) & 3);
    int k    = c * 32 + kg * 8 + j;
    float v  = (o < OOv) ? W[o * KKv + k] : 0.0f;
    union { _Float16 h; unsigned short u; } cv; cv.h = (_Float16)v;
    Wh[idx] = cv.u;
}

// ---------------------------------------------------------------------------
// Per-wave uniform staging of one K=32 chunk: 3 x 16B-slot loads + 1 x 4B
// tail load = exactly 4 vmem ops per wave per chunk (uniform -> counted vmcnt).
// Slots 0..11 split 3-per-wave (16B x 64 lanes = 1024B each); slot 12 split
// 256B-per-wave at width 4.
// ---------------------------------------------------------------------------
__device__ __forceinline__ void stage_chunk(const char* src, unsigned char* dst,
                                            int s16off0, int s4off) {
#pragma unroll
    for (int q = 0; q < 3; ++q) {
        const int off = s16off0 + q * 1024;
        __builtin_amdgcn_global_load_lds(
            (const __attribute__((address_space(1))) unsigned int*)(src + off),
            (__attribute__((address_space(3))) unsigned int*)(dst + off),
            16, 0, 0);
    }
    __builtin_amdgcn_global_load_lds(
        (const __attribute__((address_space(1))) unsigned int*)(src + s4off),
        (__attribute__((address_space(3))) unsigned int*)(dst + s4off),
        4, 0, 0);
}

// ---------------------------------------------------------------------------
// One K=32 step of the pipelined loop.
//  (1) yv reads (ylds immutable -> legal & latency-hidden pre-barrier)
//  (2) counted vmcnt (clobber-free asm, per the verified 8-phase template):
//      own 4 stage-ops of THIS chunk retired; the next 2 chunks' loads stay
//      in flight across the barrier (T4)
//  (3) sched_barrier(0) fences, then raw s_barrier publishes this chunk's
//      LDS (rule #18: s_barrier is not a compiler fence on its own)
//  (4) issue prefetch for chunk c+3 into the buffer chunk c-1 just vacated
//      (race-free: all waves' reads of that buffer retired -- their data fed
//      MFMAs that executed before this barrier in program order)
//  (5) bf reads + af build + MFMA cluster under setprio(1) (T5)
// ---------------------------------------------------------------------------
template<int P, int VM, bool STAGE>
__device__ __forceinline__ void chunk_step(
        unsigned bufc, unsigned bufs, unsigned char* bsm,
        const char* wsrc, int s16off0, int s4off,
        const char* (&ybase)[4], half2v (&xd)[4][8],
        int bfoff, int ntiles, bool w1, bool w2, bool w3,
        floatx4 (&acc)[4][7])
{
    constexpr int R32a[5] = {0, 64, 48, 32, 16};  // (32p mod 40) in bytes
    constexpr int B5a[5]  = {0, 0, 1, 2, 3};
    constexpr int WKa[5]  = {0, 1, 2, 3, 0};
    constexpr int pm = P % 5, pd = P / 5;
    constexpr int yimm  = R32a[pm];
    constexpr int dbase = B5a[pm] + 4 * pd;
    constexpr int wk    = WKa[pm];
    const bool use = (wk == 1) ? w1 : (wk == 2) ? w2 : (wk == 3) ? w3 : false;

    // (1) y fragments, pre-barrier (ylds is never rewritten)
    half8 yv[4];
#pragma unroll
    for (int rt = 0; rt < 4; ++rt)
        yv[rt] = *(const half8*)(ybase[rt] + (yimm - (use ? 80 : 0)));

    // (2) counted wait -- never drains the deep prefetch except at tail
    if constexpr (VM == 8)      asm volatile("s_waitcnt vmcnt(8)");
    else if constexpr (VM == 4) asm volatile("s_waitcnt vmcnt(4)");
    else                        asm volatile("s_waitcnt vmcnt(0)");
    __builtin_amdgcn_sched_barrier(0);
    // (3)
    __builtin_amdgcn_s_barrier();
    __builtin_amdgcn_sched_barrier(0);

    // (4) prefetch chunk c+3
    if constexpr (STAGE) stage_chunk(wsrc, bsm + bufs, s16off0, s4off);

    // (5) B fragments from the now-published chunk
    const unsigned char* chunk = bsm + bufc;
    half8 bf[7];
#pragma unroll
    for (int ct = 0; ct < 7; ++ct)
        if (ct < ntiles)
            bf[ct] = *(const half8*)(chunk + bfoff + ct * 1024);

    half8 af[4];
#pragma unroll
    for (int rt = 0; rt < 4; ++rt) {
        half2v xs = use ? xd[rt][dbase + 1] : xd[rt][dbase];
        half8 xsp = __builtin_shufflevector(xs, xs, 0, 1, 0, 1, 0, 1, 0, 1);
        af[rt] = xsp * yv[rt];
    }

    __builtin_amdgcn_s_setprio(1);
#pragma unroll
    for (int ct = 0; ct < 7; ++ct)
        if (ct < ntiles)
#pragma unroll
            for (int rt = 0; rt < 4; ++rt)
                acc[rt][ct] = __builtin_amdgcn_mfma_f32_16x16x32_f16(
                    af[rt], bf[ct], acc[rt][ct], 0, 0, 0);
    __builtin_amdgcn_s_setprio(0);
}

// ---------------------------------------------------------------------------
// Main kernel: 512 blocks x 256 thr, 128 rows x 208 cols per block.
// W flows through a 4-chunk LDS ring; 1 raw barrier per K=32 step (50 total),
// vmcnt(8) steady-state so 2 chunks of prefetch live across every barrier.
// Buffer index is compile-time: chunk c -> ring slot (c & 3); the b0..b3
// pointer rotation by 2 per 10-chunk group keeps that mapping static
// (10 = 2 mod 4; 4 groups = rotation 8 = identity, so the peeled 5th group
// reuses the initial mapping).
// ---------------------------------------------------------------------------
__global__ __launch_bounds__(256, 2) void cin_mfma_kernel(
        const float* __restrict__ X, const float* __restrict__ Y,
        const unsigned short* __restrict__ Wh, float* __restrict__ Out) {
    __shared__ __align__(16) unsigned char bsm[4 * CHUNK_BYTES];   // 53248
    __shared__ __align__(16) _Float16 xlds[128 * XSTR];            // 10240
    __shared__ __align__(16) _Float16 ylds[128 * YSTR];            // 14336

    const int tid     = threadIdx.x;
    const int wave    = tid >> 6;
    const int lane    = tid & 63;
    const int li      = lane & 15;
    const int kg      = lane >> 4;
    const int rowhalf = wave & 1;
    const int colgrp  = wave >> 1;
    const int ntiles  = colgrp ? 6 : 7;
    const int obase   = colgrp * 112;
    const long blockbase = (long)blockIdx.x * 128;

    // ---- prologue: stage x,y (128 rows x 40) as fp16
    const float* xg = X + blockbase * 40;
    const float* yg = Y + blockbase * 40;
    for (int i = tid; i < 1280; i += 256) {
        int r  = i / 10;
        int c4 = (i % 10) * 4;                 // 40 % 4 == 0: row-aligned
        floatx4 vx = *(const floatx4*)(xg + i * 4);
        floatx4 vy = *(const floatx4*)(yg + i * 4);
        union { half2v h[2]; unsigned long long u; } px, py;
        px.h[0] = (half2v){(_Float16)vx.x, (_Float16)vx.y};
        px.h[1] = (half2v){(_Float16)vx.z, (_Float16)vx.w};
        py.h[0] = (half2v){(_Float16)vy.x, (_Float16)vy.y};
        py.h[1] = (half2v){(_Float16)vy.z, (_Float16)vy.w};
        *(unsigned long long*)(xlds + r * XSTR + c4) = px.u;
        *(unsigned long long*)(ylds + r * YSTR + c4) = py.u;
    }

    // stage W chunks 0..2 (12 vmem ops in flight, NOT drained at the barrier)
    const int s16off0 = wave * 3 * 1024 + lane * 16;
    const int s4off   = 12 * 1024 + wave * 256 + lane * 4;
    {
        const char* src = (const char*)Wh;
#pragma unroll
        for (int c0 = 0; c0 < 3; ++c0)
            stage_chunk(src + c0 * CHUNK_BYTES, bsm + c0 * CHUNK_BYTES,
                        s16off0, s4off);
    }
    // publish x/y (lgkm only) -- deliberately NO vmcnt drain here
    asm volatile("s_waitcnt lgkmcnt(0)");
    __builtin_amdgcn_sched_barrier(0);
    __builtin_amdgcn_s_barrier();
    __builtin_amdgcn_sched_barrier(0);

    floatx4 acc[4][7];
#pragma unroll
    for (int rt = 0; rt < 4; ++rt)
#pragma unroll
        for (int ct = 0; ct < 7; ++ct)
            acc[rt][ct] = (floatx4){0.f, 0.f, 0.f, 0.f};

    const int rowb = rowhalf * 64 + li;
    const char* ybase[4];
    const char* xbase[4];
#pragma unroll
    for (int rt = 0; rt < 4; ++rt) {
        int row = rowb + rt * 16;
        ybase[rt] = (const char*)ylds + row * (YSTR * 2) + kg * 16;
        xbase[rt] = (const char*)xlds + row * (XSTR * 2);
    }
    const bool w1 = kg >= 1, w2 = kg >= 2, w3 = kg >= 3;

    // per-lane B-frag offset inside a chunk (swizzled slots, bank-uniform)
    const int bfoff = (obase + li) * 64 + ((kg ^ ((li >> 1) & 3)) * 16);

    unsigned b0 = 0 * CHUNK_BYTES, b1 = 1 * CHUNK_BYTES;
    unsigned b2 = 2 * CHUNK_BYTES, b3 = 3 * CHUNK_BYTES;
    const char* wsrc = (const char*)Wh + 3 * CHUNK_BYTES;   // next chunk to stage

#define CSTEP(PP, VMV, ST, BC, BS) \
    chunk_step<PP, VMV, ST>(BC, BS, bsm, wsrc + PP * CHUNK_BYTES, s16off0, s4off, \
                            ybase, xd, bfoff, ntiles, w1, w2, w3, acc)

#pragma unroll 1
    for (int g = 0; g < 4; ++g) {
        // x window for this group: elements 8g..8g+7 per row, pre-dup'd
        half2v xd[4][8];
#pragma unroll
        for (int rt = 0; rt < 4; ++rt) {
            half8 xq = *(const half8*)(xbase[rt] + g * 16);
#pragma unroll
            for (int e = 0; e < 8; ++e)
                xd[rt][e] = (half2v){xq[e], xq[e]};
        }
        CSTEP(0, 8, true, b0, b3);
        CSTEP(1, 8, true, b1, b0);
        CSTEP(2, 8, true, b2, b1);
        CSTEP(3, 8, true, b3, b2);
        CSTEP(4, 8, true, b0, b3);
        CSTEP(5, 8, true, b1, b0);
        CSTEP(6, 8, true, b2, b1);
        CSTEP(7, 8, true, b3, b2);
        CSTEP(8, 8, true, b0, b3);
        CSTEP(9, 8, true, b1, b0);
        wsrc += 10 * CHUNK_BYTES;
        unsigned t0 = b0, t1 = b1; b0 = b2; b1 = b3; b2 = t0; b3 = t1;
    }
    // ---- peeled group g=4 (chunks 40..49): tail of the prefetch pipeline.
    // Rotation is back to identity here (4 x rot2 = 0 mod 4).
    {
        half2v xd[4][8];
#pragma unroll
        for (int rt = 0; rt < 4; ++rt) {
            half8 xq = *(const half8*)(xbase[rt] + 4 * 16);
#pragma unroll
            for (int e = 0; e < 8; ++e)
                xd[rt][e] = (half2v){xq[e], xq[e]};
        }
        CSTEP(0, 8, true,  b0, b3);   // c=40, stages 43
        CSTEP(1, 8, true,  b1, b0);   // 41 -> 44
        CSTEP(2, 8, true,  b2, b1);   // 42 -> 45
        CSTEP(3, 8, true,  b3, b2);   // 43 -> 46
        CSTEP(4, 8, true,  b0, b3);   // 44 -> 47
        CSTEP(5, 8, true,  b1, b0);   // 45 -> 48
        CSTEP(6, 8, true,  b2, b1);   // 46 -> 49 (last stage)
        CSTEP(7, 8, false, b3, b2);   // 47: 48,49 still in flight (8 ops)
        CSTEP(8, 4, false, b0, b3);   // 48: 49 in flight (4 ops)
        CSTEP(9, 0, false, b1, b0);   // 49: full drain
    }
#undef CSTEP

    // ---- epilogue: C/D layout col = lane&15, row = (lane>>4)*4 + reg  [m89]
#pragma unroll
    for (int rt = 0; rt < 4; ++rt) {
#pragma unroll
        for (int ct = 0; ct < 7; ++ct) {
            if (ct >= ntiles) continue;
            int gcol = obase + ct * 16 + li;
            if (gcol < OOv) {
#pragma unroll
                for (int r4 = 0; r4 < 4; ++r4) {
                    long grow = blockbase + rowhalf * 64 + rt * 16 + kg * 4 + r4;
                    Out[grow * OOv + gcol] = acc[rt][ct][r4];
                }
            }
        }
    }
}

extern "C" void kernel_launch(void* const* d_in, const int* in_sizes, int n_in,
                              void* d_out, int out_size, void* d_ws, size_t ws_size,
                              hipStream_t stream) {
    (void)in_sizes; (void)n_in; (void)out_size; (void)ws_size;
    const float* X = (const float*)d_in[0];
    const float* Y = (const float*)d_in[1];
    const float* W = (const float*)d_in[2];
    float* Out = (float*)d_out;
    unsigned short* Wh = (unsigned short*)d_ws;   // 665,600 B scratch

    wb_convert_kernel<<<1300, 256, 0, stream>>>(W, Wh);
    cin_mfma_kernel<<<512, 256, 0, stream>>>(X, Y, Wh, Out);
}

// Round 3
// 127.471 us; speedup vs baseline: 1.1069x; 1.1069x over previous
//
#include <hip/hip_runtime.h>
#include <hip/hip_fp16.h>

// Problem constants
#define OOv   200
#define KKv   1600
#define OPAD  208             // 13 col-tiles of 16
#define NCHUNK 50             // K=32 chunks
#define CHUNK_BYTES 13312     // one K=32 chunk of W-fp16 (208*4 slots * 16B)
#define XSTR 40               // halfs per x row (80 B, mult of 16)
#define YSTR 56               // halfs per y row (112 B; 28-dw stride = 2-way banks, free)

typedef _Float16 half8  __attribute__((ext_vector_type(8)));
typedef _Float16 half2v __attribute__((ext_vector_type(2)));
typedef __attribute__((ext_vector_type(4))) float floatx4;

// ---------------------------------------------------------------------------
// Pre-kernel: W [200][1600] fp32 -> Wh fp16, K-chunk-major, 16B-slot swizzled.
// idx = c*6656 + slot*8 + j ; slot = o*4 + (kg ^ ((o>>1)&3)) ; k = c*32+kg*8+j
// ---------------------------------------------------------------------------
__global__ void wb_convert_kernel(const float* __restrict__ W,
                                  unsigned short* __restrict__ Wh) {
    int idx = blockIdx.x * 256 + threadIdx.x;
    if (idx >= NCHUNK * OPAD * 32) return;     // 332800
    int j    = idx & 7;
    int slot = (idx >> 3) % (OPAD * 4);
    int c    = (idx >> 3) / (OPAD * 4);
    int o    = slot >> 2;
    int kgs  = slot & 3;
    int kg   = kgs ^ ((o >> 1) & 3);
    int k    = c * 32 + kg * 8 + j;
    float v  = (o < OOv) ? W[o * KKv + k] : 0.0f;
    union { _Float16 h; unsigned short u; } cv; cv.h = (_Float16)v;
    Wh[idx] = cv.u;
}

// ---------------------------------------------------------------------------
// Per-wave uniform staging of one K=32 chunk: 3 x 16B-slot loads + 1 x 4B
// tail load = exactly 4 vmem ops per wave per chunk (uniform -> counted vmcnt).
// ---------------------------------------------------------------------------
__device__ __forceinline__ void stage_chunk(const char* src, unsigned char* dst,
                                            int s16off0, int s4off) {
#pragma unroll
    for (int q = 0; q < 3; ++q) {
        const int off = s16off0 + q * 1024;
        __builtin_amdgcn_global_load_lds(
            (const __attribute__((address_space(1))) unsigned int*)(src + off),
            (__attribute__((address_space(3))) unsigned int*)(dst + off),
            16, 0, 0);
    }
    __builtin_amdgcn_global_load_lds(
        (const __attribute__((address_space(1))) unsigned int*)(src + s4off),
        (__attribute__((address_space(3))) unsigned int*)(dst + s4off),
        4, 0, 0);
}

// ---------------------------------------------------------------------------
// One K=32 step. Order (anti-LDS-DMA-alias-stall):
//  (1) yv reads pre-barrier (ylds immutable)
//  (2) manual vmcnt(VM): cross-wave publish guarantee for chunk c's stage
//  (3) sched_barrier + s_barrier + sched_barrier (rule #18 fences)
//  (4) bf ds_reads from the DISTINCT shared array rd  <-- BEFORE the stage
//      issue, so even a conservative compiler wait never covers the
//      freshly-issued prefetch; with distinct objects it covers nothing.
//  (5) stage chunk c+3 into distinct array st (slot vacated pre-barrier)
//  (6) af build + MFMA cluster under setprio(1)
// ---------------------------------------------------------------------------
template<int P, int VM, bool STAGE>
__device__ __forceinline__ void chunk_step(
        const unsigned char (&rd)[CHUNK_BYTES],
        unsigned char (&st)[CHUNK_BYTES],
        const char* wsrc, int s16off0, int s4off,
        const char* (&ybase)[4], half2v (&xd)[4][8],
        int bfoff, int ntiles, bool w1, bool w2, bool w3,
        floatx4 (&acc)[4][7])
{
    constexpr int R32a[5] = {0, 64, 48, 32, 16};  // (32p mod 40) in bytes
    constexpr int B5a[5]  = {0, 0, 1, 2, 3};
    constexpr int WKa[5]  = {0, 1, 2, 3, 0};
    constexpr int pm = P % 5, pd = P / 5;
    constexpr int yimm  = R32a[pm];
    constexpr int dbase = B5a[pm] + 4 * pd;
    constexpr int wk    = WKa[pm];
    const bool use = (wk == 1) ? w1 : (wk == 2) ? w2 : (wk == 3) ? w3 : false;

    // (1) y fragments, pre-barrier
    half8 yv[4];
#pragma unroll
    for (int rt = 0; rt < 4; ++rt)
        yv[rt] = *(const half8*)(ybase[rt] + (yimm - (use ? 80 : 0)));

    // (2) counted wait -- retire exactly chunk c's 4 stage ops, keep the rest
    if constexpr (VM == 8)      asm volatile("s_waitcnt vmcnt(8)");
    else if constexpr (VM == 4) asm volatile("s_waitcnt vmcnt(4)");
    else                        asm volatile("s_waitcnt vmcnt(0)");
    __builtin_amdgcn_sched_barrier(0);
    // (3)
    __builtin_amdgcn_s_barrier();
    __builtin_amdgcn_sched_barrier(0);

    // (4) B fragments from the now-published chunk (distinct LDS object)
    half8 bf[7];
#pragma unroll
    for (int ct = 0; ct < 7; ++ct)
        if (ct < ntiles)
            bf[ct] = *(const half8*)(&rd[0] + bfoff + ct * 1024);

    // (5) prefetch chunk c+3 (issued AFTER the reads)
    if constexpr (STAGE) stage_chunk(wsrc, &st[0], s16off0, s4off);

    half8 af[4];
#pragma unroll
    for (int rt = 0; rt < 4; ++rt) {
        half2v xs = use ? xd[rt][dbase + 1] : xd[rt][dbase];
        half8 xsp = __builtin_shufflevector(xs, xs, 0, 1, 0, 1, 0, 1, 0, 1);
        af[rt] = xsp * yv[rt];
    }

    __builtin_amdgcn_s_setprio(1);
#pragma unroll
    for (int ct = 0; ct < 7; ++ct)
        if (ct < ntiles)
#pragma unroll
            for (int rt = 0; rt < 4; ++rt)
                acc[rt][ct] = __builtin_amdgcn_mfma_f32_16x16x32_f16(
                    af[rt], bf[ct], acc[rt][ct], 0, 0, 0);
    __builtin_amdgcn_s_setprio(0);
}

// ---------------------------------------------------------------------------
// Main kernel: 512 blocks x 256 thr, 128 rows x 208 cols per block.
// W flows through FOUR DISTINCT 1-chunk LDS arrays (so the compiler's
// LDS-DMA alias tracking can prove ds_reads of slot c&3 independent of
// in-flight DMA into the other slots). Chunk c -> slot c&3, fully static:
// 2 x 20-step unrolled iterations + 10-step peeled tail. One raw barrier per
// chunk (50); vmcnt(8) steady-state keeps 2 chunks of prefetch in flight
// across every barrier; tail peels 8 -> 4 -> 0.
// ---------------------------------------------------------------------------
__global__ __launch_bounds__(256, 2) void cin_mfma_kernel(
        const float* __restrict__ X, const float* __restrict__ Y,
        const unsigned short* __restrict__ Wh, float* __restrict__ Out) {
    __shared__ __align__(16) unsigned char bsm0[CHUNK_BYTES];
    __shared__ __align__(16) unsigned char bsm1[CHUNK_BYTES];
    __shared__ __align__(16) unsigned char bsm2[CHUNK_BYTES];
    __shared__ __align__(16) unsigned char bsm3[CHUNK_BYTES];
    __shared__ __align__(16) _Float16 xlds[128 * XSTR];            // 10240
    __shared__ __align__(16) _Float16 ylds[128 * YSTR];            // 14336

    const int tid     = threadIdx.x;
    const int wave    = tid >> 6;
    const int lane    = tid & 63;
    const int li      = lane & 15;
    const int kg      = lane >> 4;
    const int rowhalf = wave & 1;
    const int colgrp  = wave >> 1;
    const int ntiles  = colgrp ? 6 : 7;
    const int obase   = colgrp * 112;
    const long blockbase = (long)blockIdx.x * 128;

    // ---- prologue: stage x,y (128 rows x 40) as fp16
    const float* xg = X + blockbase * 40;
    const float* yg = Y + blockbase * 40;
    for (int i = tid; i < 1280; i += 256) {
        int r  = i / 10;
        int c4 = (i % 10) * 4;                 // 40 % 4 == 0: row-aligned
        floatx4 vx = *(const floatx4*)(xg + i * 4);
        floatx4 vy = *(const floatx4*)(yg + i * 4);
        union { half2v h[2]; unsigned long long u; } px, py;
        px.h[0] = (half2v){(_Float16)vx.x, (_Float16)vx.y};
        px.h[1] = (half2v){(_Float16)vx.z, (_Float16)vx.w};
        py.h[0] = (half2v){(_Float16)vy.x, (_Float16)vy.y};
        py.h[1] = (half2v){(_Float16)vy.z, (_Float16)vy.w};
        *(unsigned long long*)(xlds + r * XSTR + c4) = px.u;
        *(unsigned long long*)(ylds + r * YSTR + c4) = py.u;
    }
    __builtin_amdgcn_sched_barrier(0);   // keep x/y loads out of the W ledger

    // stage W chunks 0..2 (12 vmem ops in flight, NOT drained at the barrier)
    const int s16off0 = wave * 3 * 1024 + lane * 16;
    const int s4off   = 12 * 1024 + wave * 256 + lane * 4;
    stage_chunk((const char*)Wh + 0 * CHUNK_BYTES, &bsm0[0], s16off0, s4off);
    stage_chunk((const char*)Wh + 1 * CHUNK_BYTES, &bsm1[0], s16off0, s4off);
    stage_chunk((const char*)Wh + 2 * CHUNK_BYTES, &bsm2[0], s16off0, s4off);

    // publish x/y (lgkm only) -- deliberately NO vmcnt drain here
    asm volatile("s_waitcnt lgkmcnt(0)");
    __builtin_amdgcn_sched_barrier(0);
    __builtin_amdgcn_s_barrier();
    __builtin_amdgcn_sched_barrier(0);

    floatx4 acc[4][7];
#pragma unroll
    for (int rt = 0; rt < 4; ++rt)
#pragma unroll
        for (int ct = 0; ct < 7; ++ct)
            acc[rt][ct] = (floatx4){0.f, 0.f, 0.f, 0.f};

    const int rowb = rowhalf * 64 + li;
    const char* ybase[4];
    const char* xbase[4];
#pragma unroll
    for (int rt = 0; rt < 4; ++rt) {
        int row = rowb + rt * 16;
        ybase[rt] = (const char*)ylds + row * (YSTR * 2) + kg * 16;
        xbase[rt] = (const char*)xlds + row * (XSTR * 2);
    }
    const bool w1 = kg >= 1, w2 = kg >= 2, w3 = kg >= 3;

    // per-lane B-frag offset inside a chunk (swizzled slots, bank-uniform)
    const int bfoff = (obase + li) * 64 + ((kg ^ ((li >> 1) & 3)) * 16);

    const char* wsrc = (const char*)Wh + 3 * CHUNK_BYTES;   // next chunk to stage

#define CSTEP(PP, VMV, ST, RD, STB, OFF) \
    chunk_step<PP, VMV, ST>(RD, STB, wsrc + (OFF) * CHUNK_BYTES, s16off0, s4off, \
                            ybase, xd, bfoff, ntiles, w1, w2, w3, acc)

#pragma unroll 1
    for (int it = 0; it < 2; ++it) {
        {   // chunks 20it .. 20it+9 : x window g = 2it
            half2v xd[4][8];
#pragma unroll
            for (int rt = 0; rt < 4; ++rt) {
                half8 xq = *(const half8*)(xbase[rt] + (2 * it) * 16);
#pragma unroll
                for (int e = 0; e < 8; ++e)
                    xd[rt][e] = (half2v){xq[e], xq[e]};
            }
            CSTEP(0, 8, true, bsm0, bsm3, 0);
            CSTEP(1, 8, true, bsm1, bsm0, 1);
            CSTEP(2, 8, true, bsm2, bsm1, 2);
            CSTEP(3, 8, true, bsm3, bsm2, 3);
            CSTEP(4, 8, true, bsm0, bsm3, 4);
            CSTEP(5, 8, true, bsm1, bsm0, 5);
            CSTEP(6, 8, true, bsm2, bsm1, 6);
            CSTEP(7, 8, true, bsm3, bsm2, 7);
            CSTEP(8, 8, true, bsm0, bsm3, 8);
            CSTEP(9, 8, true, bsm1, bsm0, 9);
        }
        {   // chunks 20it+10 .. 20it+19 : x window g = 2it+1
            half2v xd[4][8];
#pragma unroll
            for (int rt = 0; rt < 4; ++rt) {
                half8 xq = *(const half8*)(xbase[rt] + (2 * it + 1) * 16);
#pragma unroll
                for (int e = 0; e < 8; ++e)
                    xd[rt][e] = (half2v){xq[e], xq[e]};
            }
            CSTEP(0, 8, true, bsm2, bsm1, 10);
            CSTEP(1, 8, true, bsm3, bsm2, 11);
            CSTEP(2, 8, true, bsm0, bsm3, 12);
            CSTEP(3, 8, true, bsm1, bsm0, 13);
            CSTEP(4, 8, true, bsm2, bsm1, 14);
            CSTEP(5, 8, true, bsm3, bsm2, 15);
            CSTEP(6, 8, true, bsm0, bsm3, 16);
            CSTEP(7, 8, true, bsm1, bsm0, 17);
            CSTEP(8, 8, true, bsm2, bsm1, 18);
            CSTEP(9, 8, true, bsm3, bsm2, 19);
        }
        wsrc += 20 * CHUNK_BYTES;
    }
    // ---- peeled tail: chunks 40..49, x window g = 4; wsrc = Wh + 43*CHUNK
    {
        half2v xd[4][8];
#pragma unroll
        for (int rt = 0; rt < 4; ++rt) {
            half8 xq = *(const half8*)(xbase[rt] + 4 * 16);
#pragma unroll
            for (int e = 0; e < 8; ++e)
                xd[rt][e] = (half2v){xq[e], xq[e]};
        }
        CSTEP(0, 8, true,  bsm0, bsm3, 0);   // c=40, stages 43
        CSTEP(1, 8, true,  bsm1, bsm0, 1);   // 41 -> 44
        CSTEP(2, 8, true,  bsm2, bsm1, 2);   // 42 -> 45
        CSTEP(3, 8, true,  bsm3, bsm2, 3);   // 43 -> 46
        CSTEP(4, 8, true,  bsm0, bsm3, 4);   // 44 -> 47
        CSTEP(5, 8, true,  bsm1, bsm0, 5);   // 45 -> 48
        CSTEP(6, 8, true,  bsm2, bsm1, 6);   // 46 -> 49 (last stage)
        CSTEP(7, 8, false, bsm3, bsm2, 0);   // 47: 48,49 in flight (8 ops)
        CSTEP(8, 4, false, bsm0, bsm3, 0);   // 48: 49 in flight (4 ops)
        CSTEP(9, 0, false, bsm1, bsm0, 0);   // 49: full drain
    }
#undef CSTEP

    // ---- epilogue: C/D layout col = lane&15, row = (lane>>4)*4 + reg  [m89]
#pragma unroll
    for (int rt = 0; rt < 4; ++rt) {
#pragma unroll
        for (int ct = 0; ct < 7; ++ct) {
            if (ct >= ntiles) continue;
            int gcol = obase + ct * 16 + li;
            if (gcol < OOv) {
#pragma unroll
                for (int r4 = 0; r4 < 4; ++r4) {
                    long grow = blockbase + rowhalf * 64 + rt * 16 + kg * 4 + r4;
                    Out[grow * OOv + gcol] = acc[rt][ct][r4];
                }
            }
        }
    }
}

extern "C" void kernel_launch(void* const* d_in, const int* in_sizes, int n_in,
                              void* d_out, int out_size, void* d_ws, size_t ws_size,
                              hipStream_t stream) {
    (void)in_sizes; (void)n_in; (void)out_size; (void)ws_size;
    const float* X = (const float*)d_in[0];
    const float* Y = (const float*)d_in[1];
    const float* W = (const float*)d_in[2];
    float* Out = (float*)d_out;
    unsigned short* Wh = (unsigned short*)d_ws;   // 665,600 B scratch

    wb_convert_kernel<<<1300, 256, 0, stream>>>(W, Wh);
    cin_mfma_kernel<<<512, 256, 0, stream>>>(X, Y, Wh, Out);
}